// Round 20
// baseline (820.257 us; speedup 1.0000x reference)
//
#include <hip/hip_runtime.h>
#include <stdint.h>

#define T_TOK 8192
#define DMODEL 1024
#define FDIM 4096
#define NEXP 8
#define NROWS 16384      // T_TOK * K
#define MAXT 80          // max 256-row tiles

// prep_kernel block ranges
#define GATE_BLKS 2048                  // T_TOK/4
#define CVT_BLKS  4096                  // T*D/8/256
#define TRP_BLKS  2048                  // 1024 w1-groups + 1024 w2-groups (8 tiles each)
#define PREP_BLKS (GATE_BLKS + CVT_BLKS + TRP_BLKS)

typedef __bf16 bf16x8 __attribute__((ext_vector_type(8)));
typedef float f32x4 __attribute__((ext_vector_type(4)));
#define AS1 __attribute__((address_space(1)))
#define AS3 __attribute__((address_space(3)))

__device__ __forceinline__ unsigned short f2bf(float f) {
  union { float f; unsigned u; } v; v.f = f;
  unsigned r = v.u + 0x7fffu + ((v.u >> 16) & 1u);
  return (unsigned short)(r >> 16);
}
__device__ __forceinline__ float bflo(unsigned u) {
  union { unsigned u; float f; } v; v.u = u << 16; return v.f;
}
__device__ __forceinline__ float bfhi(unsigned u) {
  union { unsigned u; float f; } v; v.u = u & 0xffff0000u; return v.f;
}

// ---- pipelined tile transpose (verified R18): f32 -> chunked [kt][n][64] bf16
__device__ __forceinline__ void tile_tr_pipe(
    const float* __restrict__ in, unsigned short* __restrict__ out,
    int Kdim, int Ndim, int e, int kt, int ng0, float* lds)
{
  size_t ebase = (size_t)e * Kdim * Ndim;
  const int tid = threadIdx.x, lane = tid & 63, wave = tid >> 6;
  const int lr = lane >> 4, lc = (lane & 15) * 4;
  auto stage = [&](int i, int b) {
    const int n0 = (ng0 + i) * 64;
#pragma unroll
    for (int it = 0; it < 4; ++it) {
      int c = wave * 4 + it;                        // 1KB chunk = 4 k-rows
      const float* src = in + ebase + (size_t)(kt * 64 + c * 4 + lr) * Ndim + n0 + lc;
      __builtin_amdgcn_global_load_lds(
          (const AS1 void*)src,
          (AS3 void*)((char*)lds + b * 16384 + c * 1024), 16, 0, 0);
    }
  };
  stage(0, 0);
  for (int i = 0; i < 8; ++i) {
    const int b = i & 1;
    if (i + 1 < 8) {
      stage(i + 1, b ^ 1);
      asm volatile("s_waitcnt vmcnt(4)" ::: "memory");
    } else {
      asm volatile("s_waitcnt vmcnt(0)" ::: "memory");
    }
    __syncthreads();
    const float* L = lds + b * 4096;
    int n = tid >> 2, k16 = (tid & 3) * 16;
    union { unsigned short h[16]; uint4 q[2]; } pk;
#pragma unroll
    for (int j = 0; j < 16; ++j)
      pk.h[j] = f2bf(L[(k16 + j) * 64 + n]);
    unsigned short* dst = out + ebase + ((size_t)kt * Ndim + (ng0 + i) * 64 + n) * 64 + k16;
    *(uint4*)dst = pk.q[0];
    *(uint4*)(dst + 8) = pk.q[1];
    __syncthreads();                                // phase2 done before buf reuse
  }
}

// ---------------- fused prep: gate || f32->bf16 cvt || both W transposes ------
__global__ __launch_bounds__(256) void prep_kernel(
    const float* __restrict__ gx, const float* __restrict__ Wg,
    const float* __restrict__ bg, int* __restrict__ sel,
    float* __restrict__ wts,
    const float* __restrict__ inputs, unsigned short* __restrict__ Xb,
    const float* __restrict__ w1, unsigned short* __restrict__ W1T,
    const float* __restrict__ w2, unsigned short* __restrict__ W2T)
{
  __shared__ __align__(16) float tr_lds[2 * 64 * 64];   // 32 KB dbuf
  int b = blockIdx.x;
  if (b < GATE_BLKS) {
    int t = b * 4 + (threadIdx.x >> 6);
    int lane = threadIdx.x & 63;
    const float* row = gx + (size_t)t * DMODEL;
    float acc[NEXP];
#pragma unroll
    for (int e = 0; e < NEXP; ++e) acc[e] = 0.f;
    for (int d = lane; d < DMODEL; d += 64) {
      float x = row[d];
      const float* wgr = Wg + (size_t)d * NEXP;
#pragma unroll
      for (int e = 0; e < NEXP; ++e) acc[e] += x * wgr[e];
    }
#pragma unroll
    for (int off = 32; off > 0; off >>= 1) {
#pragma unroll
      for (int e = 0; e < NEXP; ++e) acc[e] += __shfl_down(acc[e], off);
    }
    if (lane == 0) {
      float lg[NEXP];
#pragma unroll
      for (int e = 0; e < NEXP; ++e) lg[e] = acc[e] + bg[e];
      int i1 = 0; float v1 = lg[0];
#pragma unroll
      for (int e = 1; e < NEXP; ++e) if (lg[e] > v1) { v1 = lg[e]; i1 = e; }
      int i2 = -1; float v2 = -3.4e38f;
#pragma unroll
      for (int e = 0; e < NEXP; ++e) if (e != i1 && lg[e] > v2) { v2 = lg[e]; i2 = e; }
      float ez = __expf(v2 - v1);           // v2 <= v1
      float s = 1.f / (1.f + ez);
      sel[t*2] = i1; sel[t*2+1] = i2;
      wts[t*2] = s;  wts[t*2+1] = ez * s;   // no atomics: counts from sel in scan
    }
  } else if (b < GATE_BLKS + CVT_BLKS) {
    int i = (b - GATE_BLKS) * 256 + threadIdx.x;
    const float4* in4 = (const float4*)inputs;
    float4 v0 = in4[(size_t)i*2], v1 = in4[(size_t)i*2 + 1];
    union { unsigned short u[8]; uint4 q; } r;
    r.u[0]=f2bf(v0.x); r.u[1]=f2bf(v0.y); r.u[2]=f2bf(v0.z); r.u[3]=f2bf(v0.w);
    r.u[4]=f2bf(v1.x); r.u[5]=f2bf(v1.y); r.u[6]=f2bf(v1.z); r.u[7]=f2bf(v1.w);
    ((uint4*)Xb)[i] = r.q;
  } else {
    int bp = b - (GATE_BLKS + CVT_BLKS);   // 0..2047
    if (bp < 1024) {
      // w1 [E][K=1024][N=4096]: 128 groups/expert = kt(16) x nggrp(8)
      int e = bp >> 7, rem = bp & 127;
      tile_tr_pipe(w1, W1T, DMODEL, FDIM, e, rem >> 3, (rem & 7) * 8, tr_lds);
    } else {
      // w2 [E][K=4096][N=1024]: 128 groups/expert = kt(64) x nggrp(2)
      bp -= 1024;
      int e = bp >> 7, rem = bp & 127;
      tile_tr_pipe(w2, W2T, FDIM, DMODEL, e, rem >> 1, (rem & 1) * 8, tr_lds);
    }
  }
}

// ---------------- hist(sel) + offsets + 256-row tile table (1 block) ----------
__global__ __launch_bounds__(256) void scan_build_kernel(
    const int* __restrict__ sel, int* __restrict__ offsets,
    int* __restrict__ ntiles, int* __restrict__ t_e, int* __restrict__ t_r,
    int* __restrict__ t_rend)
{
  __shared__ int sc[8], soff[9], stile[9];
  int tid = threadIdx.x;
  if (tid < 8) sc[tid] = 0;
  __syncthreads();
  int cnt[NEXP];
#pragma unroll
  for (int e = 0; e < NEXP; ++e) cnt[e] = 0;
  for (int i = tid; i < NROWS; i += 256) {
    int v = sel[i];
#pragma unroll
    for (int e = 0; e < NEXP; ++e) cnt[e] += (v == e) ? 1 : 0;
  }
#pragma unroll
  for (int e = 0; e < NEXP; ++e) if (cnt[e]) atomicAdd(&sc[e], cnt[e]);
  __syncthreads();
  if (tid == 0) {
    int off = 0, tl = 0;
#pragma unroll
    for (int e = 0; e < NEXP; ++e) {
      soff[e] = off; stile[e] = tl;
      off += sc[e];
      tl += (sc[e] + 255) >> 8;
    }
    soff[8] = off; stile[8] = tl;
  }
  __syncthreads();
  int ntot = stile[8];
  for (int idx = tid; idx < ntot; idx += 256) {
    int e = 0;
#pragma unroll
    for (int q = 0; q < NEXP; ++q) if (idx >= stile[q + 1]) e = q + 1;
    int r = (idx - stile[e]) * 256;
    t_e[idx] = e; t_r[idx] = soff[e] + r; t_rend[idx] = soff[e] + sc[e];
  }
  if (tid < 9) offsets[tid] = soff[tid];
  if (tid == 0) *ntiles = ntot;
}

// ---------------- scatter: wave-aggregated per-expert atomics -----------------
__global__ __launch_bounds__(256) void scatter_kernel(
    const int* __restrict__ sel, int* __restrict__ cursors,
    const int* __restrict__ offsets, int* __restrict__ token_list,
    int* __restrict__ slot_list)
{
  int t = blockIdx.x * 256 + threadIdx.x;
  int lane = threadIdx.x & 63;
  unsigned long long ltmask = (lane == 63) ? 0x7fffffffffffffffull
                                           : ((1ull << lane) - 1ull);
#pragma unroll
  for (int k = 0; k < 2; ++k) {
    int e = sel[t*2 + k];
#pragma unroll
    for (int ex = 0; ex < NEXP; ++ex) {
      unsigned long long m = __ballot(e == ex);
      if (m == 0ull) continue;
      if (e == ex) {
        int leader = __ffsll((unsigned long long)m) - 1;
        int cnt = __popcll(m);
        int base = 0;
        if (lane == leader) base = atomicAdd(&cursors[ex], cnt);
        base = __shfl(base, leader);
        int r = offsets[ex] + base + __popcll(m & ltmask);
        token_list[r] = t;
        slot_list[r] = t*2 + k;
      }
    }
  }
}

// ---------------- grouped GEMM 256x256, BK=64: A-in-LDS, B-from-L2-to-regs ----
// LDS-BW fix: B fragments load DIRECTLY global->VGPR from the L2-resident
// chunked [kt][n][64] panel (identical bytes to old LDS rdB; XOR cancels).
// LDS holds only A (2x32KB dbuf): per-tile LDS reads 192KB -> 128KB.
// Single bR buffer, overwritten after last use (quad order 00,01,11,10:
// bR[1] dead after (1,1), bR[0] after (1,0)). Per-wave ledger (12 loads/tile:
// A-stage 4 @top, B1 4 @mid, B0 4 @end): single vmcnt(4) at tile top confirms
// A(kt)+B(kt), leaves A(kt+1) in flight. Two barriers/tile (A-LDS WAR).
template<bool G1>
__global__ __launch_bounds__(512, 2) void gemm256_kernel(
    const unsigned short* __restrict__ A, const unsigned short* __restrict__ B,
    const float* __restrict__ b1, const int* __restrict__ token_list,
    const int* __restrict__ slot_list,
    const int* __restrict__ tile_e, const int* __restrict__ tile_r,
    const int* __restrict__ tile_rend, const int* __restrict__ ntiles,
    unsigned short* __restrict__ outp)
{
  constexpr int KDIM = G1 ? DMODEL : FDIM;   // K extent
  constexpr int NKT  = KDIM / 64;
  constexpr int NOUT = G1 ? FDIM : DMODEL;   // output row width
  constexpr int KTB  = NOUT * 64;            // B k-tile stride (elements)

  int bid = blockIdx.x;
  int nb, bt;
  if constexpr (G1) {                        // 16 nb-panels: pin 2 per XCD, bt-major
    int xcd = bid & 7, idx = bid >> 3;
    nb = xcd * 2 + (idx & 1);
    bt = idx >> 1;
  } else {                                   // 4 nb-panels, bt-major
    nb = bid & 3;
    bt = bid >> 2;
  }
  if (bt >= *ntiles) return;
  const int e = tile_e[bt], row0 = tile_r[bt], rend = tile_rend[bt];
  const int n0 = nb * 256;

  const int tid = threadIdx.x, lane = tid & 63, wave = tid >> 6;
  extern __shared__ __align__(16) char smem[];   // 65536 B: A dbuf / epilogue

  const int lr8 = lane >> 3, g8 = lane & 7, ch = g8 ^ lr8;

  int mA[2];
#pragma unroll
  for (int p = 0; p < 2; ++p)
    mA[p] = (wave < 4) ? (p*64 + wave*16) : (128 + p*64 + (wave-4)*16);

  unsigned aoffs[2][2];
#pragma unroll
  for (int p = 0; p < 2; ++p)
#pragma unroll
    for (int l = 0; l < 2; ++l) {
      int m = mA[p] + l*8 + lr8;
      int row = row0 + m; if (row > NROWS - 1) row = NROWS - 1;
      int arow = G1 ? token_list[row] : row;
      aoffs[p][l] = (unsigned)arow * KDIM + ch*8;
    }

  // stage BOTH A halves of K-tile ktn (4 gload_lds/wave)
  auto stageA = [&](int ktn, int bsel) {
    char* base = smem + bsel * 32768;
    const int kb = ktn * 64;
#pragma unroll
    for (int p = 0; p < 2; ++p)
#pragma unroll
      for (int l = 0; l < 2; ++l)
        __builtin_amdgcn_global_load_lds(
            (const AS1 void*)(A + aoffs[p][l] + kb),
            (AS3 void*)(base + ((mA[p] + l*8) << 7)), 16, 0, 0);
  };

  f32x4 acc[8][4] = {};
  bf16x8 aR[4][2];        // current A-half: 4 row-frags x 2 k-slices
  bf16x8 bR[2][2][2];     // B fragments in regs: [nh][jj][ks]
  const int wr = wave >> 2, wc = wave & 3;
  const int lm = lane & 15, lk = lane >> 4, l7 = lane & 7;
  const unsigned abase = (unsigned)(wr*128 + lm) * 128;
  const unsigned kx0 = (unsigned)((lk ^ l7) << 4);
  const unsigned kx1 = (unsigned)(((4 + lk) ^ l7) << 4);

  // B global offsets (elements): fragment = chunk (ks*4+lk) of col row n
  const unsigned short* eB = B + (size_t)e * KDIM * NOUT;
  unsigned boffR[2][2][2];
#pragma unroll
  for (int nh = 0; nh < 2; ++nh)
#pragma unroll
    for (int jj = 0; jj < 2; ++jj)
#pragma unroll
      for (int ks = 0; ks < 2; ++ks)
        boffR[nh][jj][ks] =
            (unsigned)((n0 + wc*64 + nh*32 + jj*16 + lm) * 64 + (ks*4 + lk) * 8);

  auto rdA = [&](const char* base, int mh) {
#pragma unroll
    for (int i = 0; i < 4; ++i) {
      const char* pA = base + abase + mh*8192 + i*2048;
      aR[i][0] = *(const bf16x8*)(pA + kx0);
      aR[i][1] = *(const bf16x8*)(pA + kx1);
    }
  };
  auto mm = [&](int mh, int nh) {
    __builtin_amdgcn_s_setprio(1);
#pragma unroll
    for (int i = 0; i < 4; ++i)
#pragma unroll
      for (int jj = 0; jj < 2; ++jj) {
        acc[mh*4+i][nh*2+jj] = __builtin_amdgcn_mfma_f32_16x16x32_bf16(
            aR[i][0], bR[nh][jj][0], acc[mh*4+i][nh*2+jj], 0, 0, 0);
        acc[mh*4+i][nh*2+jj] = __builtin_amdgcn_mfma_f32_16x16x32_bf16(
            aR[i][1], bR[nh][jj][1], acc[mh*4+i][nh*2+jj], 0, 0, 0);
      }
    __builtin_amdgcn_s_setprio(0);
  };

  // prologue: A(0) + both B(0) halves [12 outstanding]
  stageA(0, 0);
  {
    const unsigned short* bk = eB;            // ktn = 0
#pragma unroll
    for (int jj = 0; jj < 2; ++jj)
#pragma unroll
      for (int ks = 0; ks < 2; ++ks) {
        bR[1][jj][ks] = *(const bf16x8*)(bk + boffR[1][jj][ks]);
        bR[0][jj][ks] = *(const bf16x8*)(bk + boffR[0][jj][ks]);
      }
  }

  for (int kt = 0; kt < NKT; ++kt) {
    const bool pre = (kt + 1 < NKT);
    const char* base = smem + (kt & 1) * 32768;
    const unsigned short* bkn = eB + (size_t)(kt + 1) * KTB;
    // tile top: issue A(kt+1); confirm A(kt)+B(kt) [leaves A(kt+1) in flight]
    if (pre) {
      stageA(kt + 1, (kt + 1) & 1);
      asm volatile("s_waitcnt vmcnt(4)" ::: "memory");
    } else {
      asm volatile("s_waitcnt vmcnt(0)" ::: "memory");
    }
    __builtin_amdgcn_s_barrier();
    __builtin_amdgcn_sched_barrier(0);
    rdA(base, 0);
    asm volatile("s_waitcnt lgkmcnt(0)" ::: "memory");
    __builtin_amdgcn_sched_barrier(0);
    mm(0, 0);
    mm(0, 1);
    rdA(base, 1);
    asm volatile("s_waitcnt lgkmcnt(0)" ::: "memory");
    __builtin_amdgcn_sched_barrier(0);
    mm(1, 1);
    if (pre) {                                // bR[1] dead -> load B(kt+1)[1]
#pragma unroll
      for (int jj = 0; jj < 2; ++jj)
#pragma unroll
        for (int ks = 0; ks < 2; ++ks)
          bR[1][jj][ks] = *(const bf16x8*)(bkn + boffR[1][jj][ks]);
    }
    mm(1, 0);
    if (pre) {                                // bR[0] dead -> load B(kt+1)[0]
#pragma unroll
      for (int jj = 0; jj < 2; ++jj)
#pragma unroll
        for (int ks = 0; ks < 2; ++ks)
          bR[0][jj][ks] = *(const bf16x8*)(bkn + boffR[0][jj][ks]);
    }
    __builtin_amdgcn_s_barrier();             // A-LDS WAR for next restage
    __builtin_amdgcn_sched_barrier(0);
  }

  asm volatile("" ::: "memory");
  float bias[4] = {};
  if constexpr (G1) {
#pragma unroll
    for (int j = 0; j < 4; ++j) bias[j] = b1[(size_t)e * FDIM + n0 + wc*64 + j*16 + lm];
  }

  // epilogue: 8 chunks of 32 rows; [gelu] -> f32 LDS (stride 260) -> bf16 x8
  float* eps = (float*)smem;
#pragma unroll
  for (int c = 0; c < 8; ++c) {
    __syncthreads();
    if (wr == (c >> 2)) {
#pragma unroll
      for (int ii = 0; ii < 2; ++ii) {
        const int mi = (c & 3) * 2 + ii;
#pragma unroll
        for (int j = 0; j < 4; ++j) {
#pragma unroll
          for (int r = 0; r < 4; ++r) {
            float v = acc[mi][j][r];
            if constexpr (G1) {
              v += bias[j];
              float z2 = 1.5957691216f * (v + 0.044715f * v * v * v);
              v = v / (1.f + __expf(-z2));
            }
            eps[(ii*16 + lk*4 + r) * 260 + wc*64 + j*16 + lm] = v;
          }
        }
      }
    }
    __syncthreads();
#pragma unroll
    for (int u = 0; u < 2; ++u) {
      int item = u * 512 + tid;               // 1024 items: 32 rows x 32 octs
      int lrow = item >> 5, c8 = (item & 31) * 8;
      int gr = row0 + c * 32 + lrow;
      if (gr < rend) {
        float4 v0 = *(const float4*)&eps[lrow * 260 + c8];
        float4 v1 = *(const float4*)&eps[lrow * 260 + c8 + 4];
        union { unsigned short u[8]; uint4 q; } pk;
        pk.u[0]=f2bf(v0.x); pk.u[1]=f2bf(v0.y); pk.u[2]=f2bf(v0.z); pk.u[3]=f2bf(v0.w);
        pk.u[4]=f2bf(v1.x); pk.u[5]=f2bf(v1.y); pk.u[6]=f2bf(v1.z); pk.u[7]=f2bf(v1.w);
        size_t orow;
        if constexpr (G1) orow = (size_t)gr * FDIM;
        else              orow = (size_t)slot_list[gr] * DMODEL;
        *(uint4*)(outp + orow + n0 + c8) = pk.q;
      }
    }
  }
}

// ---------------- combine: out = sum_k w_k*(y_k + b2[e_k]) --------------------
__global__ __launch_bounds__(256) void combine_kernel(
    const unsigned short* __restrict__ ys, const float* __restrict__ wts,
    const int* __restrict__ sel, const float* __restrict__ b2,
    float* __restrict__ out)
{
  int i = blockIdx.x * 256 + threadIdx.x;   // over T*D/8
  int t = i >> 7, d8 = i & 127;
  float w0 = wts[t*2], w1 = wts[t*2 + 1];
  int e0 = sel[t*2], e1 = sel[t*2 + 1];
  const uint4* ys4 = (const uint4*)ys;
  uint4 ya = ys4[(size_t)(t*2) * 128 + d8];
  uint4 yb = ys4[(size_t)(t*2 + 1) * 128 + d8];
  const float4* b24 = (const float4*)b2;
  float4 c0a = b24[e0*256 + d8*2], c0b = b24[e0*256 + d8*2 + 1];
  float4 c1a = b24[e1*256 + d8*2], c1b = b24[e1*256 + d8*2 + 1];
  float4 o0, o1;
  o0.x = w0*(bflo(ya.x)+c0a.x) + w1*(bflo(yb.x)+c1a.x);
  o0.y = w0*(bfhi(ya.x)+c0a.y) + w1*(bfhi(yb.x)+c1a.y);
  o0.z = w0*(bflo(ya.y)+c0a.z) + w1*(bflo(yb.y)+c1a.z);
  o0.w = w0*(bfhi(ya.y)+c0a.w) + w1*(bfhi(yb.y)+c1a.w);
  o1.x = w0*(bflo(ya.z)+c0b.x) + w1*(bflo(yb.z)+c1b.x);
  o1.y = w0*(bfhi(ya.z)+c0b.y) + w1*(bfhi(yb.z)+c1b.y);
  o1.z = w0*(bflo(ya.w)+c0b.z) + w1*(bflo(yb.w)+c1b.z);
  o1.w = w0*(bfhi(ya.w)+c0b.w) + w1*(bfhi(yb.w)+c1b.w);
  float4* out4 = (float4*)out;
  out4[(size_t)t * 256 + d8*2]     = o0;
  out4[(size_t)t * 256 + d8*2 + 1] = o1;
}

// ---------------- host ---------------------------------------------------------
extern "C" void kernel_launch(void* const* d_in, const int* in_sizes, int n_in,
                              void* d_out, int out_size, void* d_ws, size_t ws_size,
                              hipStream_t stream)
{
  const float* gate_inputs = (const float*)d_in[0];
  const float* inputs      = (const float*)d_in[1];
  const float* Wg          = (const float*)d_in[2];
  const float* bg          = (const float*)d_in[3];
  const float* w1          = (const float*)d_in[4];
  const float* b1          = (const float*)d_in[5];
  const float* w2          = (const float*)d_in[6];
  const float* b2          = (const float*)d_in[7];
  float* out = (float*)d_out;

  char* ws = (char*)d_ws;
  size_t o = 0;
  auto carve = [&](size_t bytes) { void* p = ws + o; o += (bytes + 255) & ~(size_t)255; return p; };
  unsigned short* Xb  = (unsigned short*)carve((size_t)T_TOK * DMODEL * 2);
  unsigned short* W1T = (unsigned short*)carve((size_t)NEXP * FDIM * DMODEL * 2);
  unsigned short* W2T = (unsigned short*)carve((size_t)NEXP * DMODEL * FDIM * 2);
  unsigned short* H   = (unsigned short*)carve((size_t)NROWS * FDIM * 2);
  unsigned short* ys  = (unsigned short*)carve((size_t)NROWS * DMODEL * 2);
  int*   sel          = (int*)carve((size_t)NROWS * 4);
  float* wts          = (float*)carve((size_t)NROWS * 4);
  int*   token_list   = (int*)carve((size_t)(NROWS + 256) * 4);
  int*   slot_list    = (int*)carve((size_t)(NROWS + 256) * 4);
  int*   ctrl         = (int*)carve(4096);
  int* cursors = ctrl + 8;        // 8
  int* offsets = ctrl + 16;       // 9
  int* ntiles  = ctrl + 28;       // 1
  int* t_e     = ctrl + 32;
  int* t_r     = ctrl + 32 + MAXT;
  int* t_rend  = ctrl + 32 + 2 * MAXT;

  hipMemsetAsync(ctrl, 0, 64, stream);  // cursors

  prep_kernel<<<PREP_BLKS, 256, 0, stream>>>(
      gate_inputs, Wg, bg, sel, wts,
      inputs, Xb, w1, W1T, w2, W2T);
  scan_build_kernel<<<1, 256, 0, stream>>>(sel, offsets, ntiles, t_e, t_r, t_rend);
  scatter_kernel<<<T_TOK / 256, 256, 0, stream>>>(sel, cursors, offsets, token_list, slot_list);

  hipFuncSetAttribute((const void*)gemm256_kernel<true>,
                      hipFuncAttributeMaxDynamicSharedMemorySize, 65536);
  hipFuncSetAttribute((const void*)gemm256_kernel<false>,
                      hipFuncAttributeMaxDynamicSharedMemorySize, 65536);
  // gemm1: H = gelu(X@W1+b1). grid = 8 xcd * (2 nb-sub * 80 bt)
  gemm256_kernel<true><<<8 * 2 * MAXT, 512, 65536, stream>>>(
      Xb, W1T, b1, token_list, nullptr, t_e, t_r, t_rend, ntiles, H);
  // gemm2: ys = H@W2 scatter. grid = 4 nb * 80 bt
  gemm256_kernel<false><<<4 * MAXT, 512, 65536, stream>>>(
      H, W2T, nullptr, nullptr, slot_list, t_e, t_r, t_rend, ntiles, ys);
  combine_kernel<<<(T_TOK * DMODEL / 8) / 256, 256, 0, stream>>>(ys, wts, sel, b2, out);
}

// Round 21
// 742.994 us; speedup vs baseline: 1.1040x; 1.1040x over previous
//
#include <hip/hip_runtime.h>
#include <stdint.h>

#define T_TOK 8192
#define DMODEL 1024
#define FDIM 4096
#define NEXP 8
#define NROWS 16384      // T_TOK * K
#define MAXT 80          // max 256-row tiles

// prep_kernel block ranges
#define GATE_BLKS 2048                  // T_TOK/4
#define CVT_BLKS  4096                  // T*D/8/256
#define TRP_BLKS  2048                  // 1024 w1-groups + 1024 w2-groups (8 tiles each)
#define PREP_BLKS (GATE_BLKS + CVT_BLKS + TRP_BLKS)

typedef __bf16 bf16x8 __attribute__((ext_vector_type(8)));
typedef float f32x4 __attribute__((ext_vector_type(4)));
#define AS1 __attribute__((address_space(1)))
#define AS3 __attribute__((address_space(3)))

__device__ __forceinline__ unsigned short f2bf(float f) {
  union { float f; unsigned u; } v; v.f = f;
  unsigned r = v.u + 0x7fffu + ((v.u >> 16) & 1u);
  return (unsigned short)(r >> 16);
}
__device__ __forceinline__ float bflo(unsigned u) {
  union { unsigned u; float f; } v; v.u = u << 16; return v.f;
}
__device__ __forceinline__ float bfhi(unsigned u) {
  union { unsigned u; float f; } v; v.u = u & 0xffff0000u; return v.f;
}
// raw global load -> VGPR quad (counts in vmcnt; NOT compiler-tracked, so the
// manual ledger governs all waits)
__device__ __forceinline__ bf16x8 gload16(const unsigned short* p) {
  bf16x8 r;
  asm volatile("global_load_dwordx4 %0, %1, off" : "=&v"(r) : "v"(p));
  return r;
}

// ---- pipelined tile transpose (verified R18): f32 -> chunked [kt][n][64] bf16
__device__ __forceinline__ void tile_tr_pipe(
    const float* __restrict__ in, unsigned short* __restrict__ out,
    int Kdim, int Ndim, int e, int kt, int ng0, float* lds)
{
  size_t ebase = (size_t)e * Kdim * Ndim;
  const int tid = threadIdx.x, lane = tid & 63, wave = tid >> 6;
  const int lr = lane >> 4, lc = (lane & 15) * 4;
  auto stage = [&](int i, int b) {
    const int n0 = (ng0 + i) * 64;
#pragma unroll
    for (int it = 0; it < 4; ++it) {
      int c = wave * 4 + it;                        // 1KB chunk = 4 k-rows
      const float* src = in + ebase + (size_t)(kt * 64 + c * 4 + lr) * Ndim + n0 + lc;
      __builtin_amdgcn_global_load_lds(
          (const AS1 void*)src,
          (AS3 void*)((char*)lds + b * 16384 + c * 1024), 16, 0, 0);
    }
  };
  stage(0, 0);
  for (int i = 0; i < 8; ++i) {
    const int b = i & 1;
    if (i + 1 < 8) {
      stage(i + 1, b ^ 1);
      asm volatile("s_waitcnt vmcnt(4)" ::: "memory");
    } else {
      asm volatile("s_waitcnt vmcnt(0)" ::: "memory");
    }
    __syncthreads();
    const float* L = lds + b * 4096;
    int n = tid >> 2, k16 = (tid & 3) * 16;
    union { unsigned short h[16]; uint4 q[2]; } pk;
#pragma unroll
    for (int j = 0; j < 16; ++j)
      pk.h[j] = f2bf(L[(k16 + j) * 64 + n]);
    unsigned short* dst = out + ebase + ((size_t)kt * Ndim + (ng0 + i) * 64 + n) * 64 + k16;
    *(uint4*)dst = pk.q[0];
    *(uint4*)(dst + 8) = pk.q[1];
    __syncthreads();                                // phase2 done before buf reuse
  }
}

// ---------------- fused prep: gate || f32->bf16 cvt || both W transposes ------
__global__ __launch_bounds__(256) void prep_kernel(
    const float* __restrict__ gx, const float* __restrict__ Wg,
    const float* __restrict__ bg, int* __restrict__ sel,
    float* __restrict__ wts,
    const float* __restrict__ inputs, unsigned short* __restrict__ Xb,
    const float* __restrict__ w1, unsigned short* __restrict__ W1T,
    const float* __restrict__ w2, unsigned short* __restrict__ W2T)
{
  __shared__ __align__(16) float tr_lds[2 * 64 * 64];   // 32 KB dbuf
  int b = blockIdx.x;
  if (b < GATE_BLKS) {
    int t = b * 4 + (threadIdx.x >> 6);
    int lane = threadIdx.x & 63;
    const float* row = gx + (size_t)t * DMODEL;
    float acc[NEXP];
#pragma unroll
    for (int e = 0; e < NEXP; ++e) acc[e] = 0.f;
    for (int d = lane; d < DMODEL; d += 64) {
      float x = row[d];
      const float* wgr = Wg + (size_t)d * NEXP;
#pragma unroll
      for (int e = 0; e < NEXP; ++e) acc[e] += x * wgr[e];
    }
#pragma unroll
    for (int off = 32; off > 0; off >>= 1) {
#pragma unroll
      for (int e = 0; e < NEXP; ++e) acc[e] += __shfl_down(acc[e], off);
    }
    if (lane == 0) {
      float lg[NEXP];
#pragma unroll
      for (int e = 0; e < NEXP; ++e) lg[e] = acc[e] + bg[e];
      int i1 = 0; float v1 = lg[0];
#pragma unroll
      for (int e = 1; e < NEXP; ++e) if (lg[e] > v1) { v1 = lg[e]; i1 = e; }
      int i2 = -1; float v2 = -3.4e38f;
#pragma unroll
      for (int e = 0; e < NEXP; ++e) if (e != i1 && lg[e] > v2) { v2 = lg[e]; i2 = e; }
      float ez = __expf(v2 - v1);           // v2 <= v1
      float s = 1.f / (1.f + ez);
      sel[t*2] = i1; sel[t*2+1] = i2;
      wts[t*2] = s;  wts[t*2+1] = ez * s;   // no atomics: counts from sel in scan
    }
  } else if (b < GATE_BLKS + CVT_BLKS) {
    int i = (b - GATE_BLKS) * 256 + threadIdx.x;
    const float4* in4 = (const float4*)inputs;
    float4 v0 = in4[(size_t)i*2], v1 = in4[(size_t)i*2 + 1];
    union { unsigned short u[8]; uint4 q; } r;
    r.u[0]=f2bf(v0.x); r.u[1]=f2bf(v0.y); r.u[2]=f2bf(v0.z); r.u[3]=f2bf(v0.w);
    r.u[4]=f2bf(v1.x); r.u[5]=f2bf(v1.y); r.u[6]=f2bf(v1.z); r.u[7]=f2bf(v1.w);
    ((uint4*)Xb)[i] = r.q;
  } else {
    int bp = b - (GATE_BLKS + CVT_BLKS);   // 0..2047
    if (bp < 1024) {
      // w1 [E][K=1024][N=4096]: 128 groups/expert = kt(16) x nggrp(8)
      int e = bp >> 7, rem = bp & 127;
      tile_tr_pipe(w1, W1T, DMODEL, FDIM, e, rem >> 3, (rem & 7) * 8, tr_lds);
    } else {
      // w2 [E][K=4096][N=1024]: 128 groups/expert = kt(64) x nggrp(2)
      bp -= 1024;
      int e = bp >> 7, rem = bp & 127;
      tile_tr_pipe(w2, W2T, FDIM, DMODEL, e, rem >> 1, (rem & 1) * 8, tr_lds);
    }
  }
}

// ---------------- hist(sel) + offsets + 256-row tile table (1 block) ----------
__global__ __launch_bounds__(256) void scan_build_kernel(
    const int* __restrict__ sel, int* __restrict__ offsets,
    int* __restrict__ ntiles, int* __restrict__ t_e, int* __restrict__ t_r,
    int* __restrict__ t_rend)
{
  __shared__ int sc[8], soff[9], stile[9];
  int tid = threadIdx.x;
  if (tid < 8) sc[tid] = 0;
  __syncthreads();
  int cnt[NEXP];
#pragma unroll
  for (int e = 0; e < NEXP; ++e) cnt[e] = 0;
  for (int i = tid; i < NROWS; i += 256) {
    int v = sel[i];
#pragma unroll
    for (int e = 0; e < NEXP; ++e) cnt[e] += (v == e) ? 1 : 0;
  }
#pragma unroll
  for (int e = 0; e < NEXP; ++e) if (cnt[e]) atomicAdd(&sc[e], cnt[e]);
  __syncthreads();
  if (tid == 0) {
    int off = 0, tl = 0;
#pragma unroll
    for (int e = 0; e < NEXP; ++e) {
      soff[e] = off; stile[e] = tl;
      off += sc[e];
      tl += (sc[e] + 255) >> 8;
    }
    soff[8] = off; stile[8] = tl;
  }
  __syncthreads();
  int ntot = stile[8];
  for (int idx = tid; idx < ntot; idx += 256) {
    int e = 0;
#pragma unroll
    for (int q = 0; q < NEXP; ++q) if (idx >= stile[q + 1]) e = q + 1;
    int r = (idx - stile[e]) * 256;
    t_e[idx] = e; t_r[idx] = soff[e] + r; t_rend[idx] = soff[e] + sc[e];
  }
  if (tid < 9) offsets[tid] = soff[tid];
  if (tid == 0) *ntiles = ntot;
}

// ---------------- scatter: wave-aggregated per-expert atomics -----------------
__global__ __launch_bounds__(256) void scatter_kernel(
    const int* __restrict__ sel, int* __restrict__ cursors,
    const int* __restrict__ offsets, int* __restrict__ token_list,
    int* __restrict__ slot_list)
{
  int t = blockIdx.x * 256 + threadIdx.x;
  int lane = threadIdx.x & 63;
  unsigned long long ltmask = (lane == 63) ? 0x7fffffffffffffffull
                                           : ((1ull << lane) - 1ull);
#pragma unroll
  for (int k = 0; k < 2; ++k) {
    int e = sel[t*2 + k];
#pragma unroll
    for (int ex = 0; ex < NEXP; ++ex) {
      unsigned long long m = __ballot(e == ex);
      if (m == 0ull) continue;
      if (e == ex) {
        int leader = __ffsll((unsigned long long)m) - 1;
        int cnt = __popcll(m);
        int base = 0;
        if (lane == leader) base = atomicAdd(&cursors[ex], cnt);
        base = __shfl(base, leader);
        int r = offsets[ex] + base + __popcll(m & ltmask);
        token_list[r] = t;
        slot_list[r] = t*2 + k;
      }
    }
  }
}

// ---------------- grouped GEMM 256x256, BK=64: A-in-LDS, B-via-asm-regs -------
// R20 fix: quad order (0,1),(1,1),(1,0),(0,0) gives each bR half >=2 quads of
// load->use distance; ALL VMEM is builtin/asm so ONE manual ledger rules.
// Per-wave loads/tile: A-stage 4 @top, B1(kt+1) 4 @mid, B0(kt+1) 4 @end.
// Steady waits: top vmcnt(12)=A(kt); pre-mm(0,1) vmcnt(8)=B1(kt);
// pre-mm(1,0) vmcnt(8)=B0(kt). Tail: 8/4/0. A re-read at quad4 (A0).
// B in private regs -> no cross-wave hazard; A dbuf WAR = 2 barriers/tile.
template<bool G1>
__global__ __launch_bounds__(512, 2) void gemm256_kernel(
    const unsigned short* __restrict__ A, const unsigned short* __restrict__ B,
    const float* __restrict__ b1, const int* __restrict__ token_list,
    const int* __restrict__ slot_list,
    const int* __restrict__ tile_e, const int* __restrict__ tile_r,
    const int* __restrict__ tile_rend, const int* __restrict__ ntiles,
    unsigned short* __restrict__ outp)
{
  constexpr int KDIM = G1 ? DMODEL : FDIM;   // K extent
  constexpr int NKT  = KDIM / 64;
  constexpr int NOUT = G1 ? FDIM : DMODEL;   // output row width
  constexpr int KTB  = NOUT * 64;            // B k-tile stride (elements)

  int bid = blockIdx.x;
  int nb, bt;
  if constexpr (G1) {                        // 16 nb-panels: pin 2 per XCD, bt-major
    int xcd = bid & 7, idx = bid >> 3;
    nb = xcd * 2 + (idx & 1);
    bt = idx >> 1;
  } else {                                   // 4 nb-panels, bt-major
    nb = bid & 3;
    bt = bid >> 2;
  }
  if (bt >= *ntiles) return;
  const int e = tile_e[bt], row0 = tile_r[bt], rend = tile_rend[bt];
  const int n0 = nb * 256;

  const int tid = threadIdx.x, lane = tid & 63, wave = tid >> 6;
  extern __shared__ __align__(16) char smem[];   // 65536 B: A dbuf / epilogue

  const int lr8 = lane >> 3, g8 = lane & 7, ch = g8 ^ lr8;

  int mA[2];
#pragma unroll
  for (int p = 0; p < 2; ++p)
    mA[p] = (wave < 4) ? (p*64 + wave*16) : (128 + p*64 + (wave-4)*16);

  unsigned aoffs[2][2];
#pragma unroll
  for (int p = 0; p < 2; ++p)
#pragma unroll
    for (int l = 0; l < 2; ++l) {
      int m = mA[p] + l*8 + lr8;
      int row = row0 + m; if (row > NROWS - 1) row = NROWS - 1;
      int arow = G1 ? token_list[row] : row;
      aoffs[p][l] = (unsigned)arow * KDIM + ch*8;
    }

  // stage BOTH A halves of K-tile ktn (4 gload_lds/wave)
  auto stageA = [&](int ktn, int bsel) {
    char* base = smem + bsel * 32768;
    const int kb = ktn * 64;
#pragma unroll
    for (int p = 0; p < 2; ++p)
#pragma unroll
      for (int l = 0; l < 2; ++l)
        __builtin_amdgcn_global_load_lds(
            (const AS1 void*)(A + aoffs[p][l] + kb),
            (AS3 void*)(base + ((mA[p] + l*8) << 7)), 16, 0, 0);
  };

  f32x4 acc[8][4] = {};
  bf16x8 aR[4][2];        // current A-half: 4 row-frags x 2 k-slices
  bf16x8 bR[2][2][2];     // B fragments in regs: [nh][jj][ks]
  const int wr = wave >> 2, wc = wave & 3;
  const int lm = lane & 15, lk = lane >> 4, l7 = lane & 7;
  const unsigned abase = (unsigned)(wr*128 + lm) * 128;
  const unsigned kx0 = (unsigned)((lk ^ l7) << 4);
  const unsigned kx1 = (unsigned)(((4 + lk) ^ l7) << 4);

  // B global offsets (elements): fragment = chunk (ks*4+lk) of col row n
  const unsigned short* eB = B + (size_t)e * KDIM * NOUT;
  unsigned boffR[2][2][2];
#pragma unroll
  for (int nh = 0; nh < 2; ++nh)
#pragma unroll
    for (int jj = 0; jj < 2; ++jj)
#pragma unroll
      for (int ks = 0; ks < 2; ++ks)
        boffR[nh][jj][ks] =
            (unsigned)((n0 + wc*64 + nh*32 + jj*16 + lm) * 64 + (ks*4 + lk) * 8);

  auto rdA = [&](const char* base, int mh) {
#pragma unroll
    for (int i = 0; i < 4; ++i) {
      const char* pA = base + abase + mh*8192 + i*2048;
      aR[i][0] = *(const bf16x8*)(pA + kx0);
      aR[i][1] = *(const bf16x8*)(pA + kx1);
    }
  };
  auto ldB = [&](int nh, const unsigned short* bk) {
#pragma unroll
    for (int jj = 0; jj < 2; ++jj)
#pragma unroll
      for (int ks = 0; ks < 2; ++ks)
        bR[nh][jj][ks] = gload16(bk + boffR[nh][jj][ks]);
  };
  auto mm = [&](int mh, int nh) {
    __builtin_amdgcn_s_setprio(1);
#pragma unroll
    for (int i = 0; i < 4; ++i)
#pragma unroll
      for (int jj = 0; jj < 2; ++jj) {
        acc[mh*4+i][nh*2+jj] = __builtin_amdgcn_mfma_f32_16x16x32_bf16(
            aR[i][0], bR[nh][jj][0], acc[mh*4+i][nh*2+jj], 0, 0, 0);
        acc[mh*4+i][nh*2+jj] = __builtin_amdgcn_mfma_f32_16x16x32_bf16(
            aR[i][1], bR[nh][jj][1], acc[mh*4+i][nh*2+jj], 0, 0, 0);
      }
    __builtin_amdgcn_s_setprio(0);
  };

  // prologue (ledger order A, B1, B0 -> 12 outstanding)
  stageA(0, 0);
  ldB(1, eB);
  ldB(0, eB);
  __builtin_amdgcn_sched_barrier(0);

  for (int kt = 0; kt < NKT; ++kt) {
    const bool pre = (kt + 1 < NKT);
    const char* base = smem + (kt & 1) * 32768;
    const unsigned short* bkn = eB + (size_t)(kt + 1) * KTB;
    // top: issue A(kt+1); confirm A(kt)
    if (pre) {
      stageA(kt + 1, (kt + 1) & 1);
      asm volatile("s_waitcnt vmcnt(12)" ::: "memory");
    } else {
      asm volatile("s_waitcnt vmcnt(8)" ::: "memory");
    }
    __builtin_amdgcn_s_barrier();
    __builtin_amdgcn_sched_barrier(0);
    // Q1 (0,1): needs A0 + bR[1](kt)
    rdA(base, 0);
    asm volatile("s_waitcnt lgkmcnt(0)" ::: "memory");
    if (pre) asm volatile("s_waitcnt vmcnt(8)" ::: "memory");
    else     asm volatile("s_waitcnt vmcnt(4)" ::: "memory");
    __builtin_amdgcn_sched_barrier(0);
    mm(0, 1);
    // Q2 (1,1): needs A1 (bR[1] still live)
    rdA(base, 1);
    asm volatile("s_waitcnt lgkmcnt(0)" ::: "memory");
    __builtin_amdgcn_sched_barrier(0);
    mm(1, 1);
    // bR[1] dead -> load B1(kt+1)
    if (pre) ldB(1, bkn);
    __builtin_amdgcn_sched_barrier(0);
    // Q3 (1,0): needs bR[0](kt)
    if (pre) asm volatile("s_waitcnt vmcnt(8)" ::: "memory");
    else     asm volatile("s_waitcnt vmcnt(0)" ::: "memory");
    __builtin_amdgcn_sched_barrier(0);
    mm(1, 0);
    // Q4 (0,0): A0 again (bR[0] still live)
    rdA(base, 0);
    asm volatile("s_waitcnt lgkmcnt(0)" ::: "memory");
    __builtin_amdgcn_sched_barrier(0);
    mm(0, 0);
    // bR[0] dead -> load B0(kt+1)
    if (pre) ldB(0, bkn);
    __builtin_amdgcn_s_barrier();             // A-LDS WAR for next restage
    __builtin_amdgcn_sched_barrier(0);
  }

  asm volatile("" ::: "memory");
  float bias[4] = {};
  if constexpr (G1) {
#pragma unroll
    for (int j = 0; j < 4; ++j) bias[j] = b1[(size_t)e * FDIM + n0 + wc*64 + j*16 + lm];
  }

  // epilogue: 8 chunks of 32 rows; [gelu] -> f32 LDS (stride 260) -> bf16 x8
  float* eps = (float*)smem;
#pragma unroll
  for (int c = 0; c < 8; ++c) {
    __syncthreads();
    if (wr == (c >> 2)) {
#pragma unroll
      for (int ii = 0; ii < 2; ++ii) {
        const int mi = (c & 3) * 2 + ii;
#pragma unroll
        for (int j = 0; j < 4; ++j) {
#pragma unroll
          for (int r = 0; r < 4; ++r) {
            float v = acc[mi][j][r];
            if constexpr (G1) {
              v += bias[j];
              float z2 = 1.5957691216f * (v + 0.044715f * v * v * v);
              v = v / (1.f + __expf(-z2));
            }
            eps[(ii*16 + lk*4 + r) * 260 + wc*64 + j*16 + lm] = v;
          }
        }
      }
    }
    __syncthreads();
#pragma unroll
    for (int u = 0; u < 2; ++u) {
      int item = u * 512 + tid;               // 1024 items: 32 rows x 32 octs
      int lrow = item >> 5, c8 = (item & 31) * 8;
      int gr = row0 + c * 32 + lrow;
      if (gr < rend) {
        float4 v0 = *(const float4*)&eps[lrow * 260 + c8];
        float4 v1 = *(const float4*)&eps[lrow * 260 + c8 + 4];
        union { unsigned short u[8]; uint4 q; } pk;
        pk.u[0]=f2bf(v0.x); pk.u[1]=f2bf(v0.y); pk.u[2]=f2bf(v0.z); pk.u[3]=f2bf(v0.w);
        pk.u[4]=f2bf(v1.x); pk.u[5]=f2bf(v1.y); pk.u[6]=f2bf(v1.z); pk.u[7]=f2bf(v1.w);
        size_t orow;
        if constexpr (G1) orow = (size_t)gr * FDIM;
        else              orow = (size_t)slot_list[gr] * DMODEL;
        *(uint4*)(outp + orow + n0 + c8) = pk.q;
      }
    }
  }
}

// ---------------- combine: out = sum_k w_k*(y_k + b2[e_k]) --------------------
__global__ __launch_bounds__(256) void combine_kernel(
    const unsigned short* __restrict__ ys, const float* __restrict__ wts,
    const int* __restrict__ sel, const float* __restrict__ b2,
    float* __restrict__ out)
{
  int i = blockIdx.x * 256 + threadIdx.x;   // over T*D/8
  int t = i >> 7, d8 = i & 127;
  float w0 = wts[t*2], w1 = wts[t*2 + 1];
  int e0 = sel[t*2], e1 = sel[t*2 + 1];
  const uint4* ys4 = (const uint4*)ys;
  uint4 ya = ys4[(size_t)(t*2) * 128 + d8];
  uint4 yb = ys4[(size_t)(t*2 + 1) * 128 + d8];
  const float4* b24 = (const float4*)b2;
  float4 c0a = b24[e0*256 + d8*2], c0b = b24[e0*256 + d8*2 + 1];
  float4 c1a = b24[e1*256 + d8*2], c1b = b24[e1*256 + d8*2 + 1];
  float4 o0, o1;
  o0.x = w0*(bflo(ya.x)+c0a.x) + w1*(bflo(yb.x)+c1a.x);
  o0.y = w0*(bfhi(ya.x)+c0a.y) + w1*(bfhi(yb.x)+c1a.y);
  o0.z = w0*(bflo(ya.y)+c0a.z) + w1*(bflo(yb.y)+c1a.z);
  o0.w = w0*(bfhi(ya.y)+c0a.w) + w1*(bfhi(yb.y)+c1a.w);
  o1.x = w0*(bflo(ya.z)+c0b.x) + w1*(bflo(yb.z)+c1b.x);
  o1.y = w0*(bfhi(ya.z)+c0b.y) + w1*(bfhi(yb.z)+c1b.y);
  o1.z = w0*(bflo(ya.w)+c0b.z) + w1*(bflo(yb.w)+c1b.z);
  o1.w = w0*(bfhi(ya.w)+c0b.w) + w1*(bfhi(yb.w)+c1b.w);
  float4* out4 = (float4*)out;
  out4[(size_t)t * 256 + d8*2]     = o0;
  out4[(size_t)t * 256 + d8*2 + 1] = o1;
}

// ---------------- host ---------------------------------------------------------
extern "C" void kernel_launch(void* const* d_in, const int* in_sizes, int n_in,
                              void* d_out, int out_size, void* d_ws, size_t ws_size,
                              hipStream_t stream)
{
  const float* gate_inputs = (const float*)d_in[0];
  const float* inputs      = (const float*)d_in[1];
  const float* Wg          = (const float*)d_in[2];
  const float* bg          = (const float*)d_in[3];
  const float* w1          = (const float*)d_in[4];
  const float* b1          = (const float*)d_in[5];
  const float* w2          = (const float*)d_in[6];
  const float* b2          = (const float*)d_in[7];
  float* out = (float*)d_out;

  char* ws = (char*)d_ws;
  size_t o = 0;
  auto carve = [&](size_t bytes) { void* p = ws + o; o += (bytes + 255) & ~(size_t)255; return p; };
  unsigned short* Xb  = (unsigned short*)carve((size_t)T_TOK * DMODEL * 2);
  unsigned short* W1T = (unsigned short*)carve((size_t)NEXP * FDIM * DMODEL * 2);
  unsigned short* W2T = (unsigned short*)carve((size_t)NEXP * DMODEL * FDIM * 2);
  unsigned short* H   = (unsigned short*)carve((size_t)NROWS * FDIM * 2);
  unsigned short* ys  = (unsigned short*)carve((size_t)NROWS * DMODEL * 2);
  int*   sel          = (int*)carve((size_t)NROWS * 4);
  float* wts          = (float*)carve((size_t)NROWS * 4);
  int*   token_list   = (int*)carve((size_t)(NROWS + 256) * 4);
  int*   slot_list    = (int*)carve((size_t)(NROWS + 256) * 4);
  int*   ctrl         = (int*)carve(4096);
  int* cursors = ctrl + 8;        // 8
  int* offsets = ctrl + 16;       // 9
  int* ntiles  = ctrl + 28;       // 1
  int* t_e     = ctrl + 32;
  int* t_r     = ctrl + 32 + MAXT;
  int* t_rend  = ctrl + 32 + 2 * MAXT;

  hipMemsetAsync(ctrl, 0, 64, stream);  // cursors

  prep_kernel<<<PREP_BLKS, 256, 0, stream>>>(
      gate_inputs, Wg, bg, sel, wts,
      inputs, Xb, w1, W1T, w2, W2T);
  scan_build_kernel<<<1, 256, 0, stream>>>(sel, offsets, ntiles, t_e, t_r, t_rend);
  scatter_kernel<<<T_TOK / 256, 256, 0, stream>>>(sel, cursors, offsets, token_list, slot_list);

  hipFuncSetAttribute((const void*)gemm256_kernel<true>,
                      hipFuncAttributeMaxDynamicSharedMemorySize, 65536);
  hipFuncSetAttribute((const void*)gemm256_kernel<false>,
                      hipFuncAttributeMaxDynamicSharedMemorySize, 65536);
  // gemm1: H = gelu(X@W1+b1). grid = 8 xcd * (2 nb-sub * 80 bt)
  gemm256_kernel<true><<<8 * 2 * MAXT, 512, 65536, stream>>>(
      Xb, W1T, b1, token_list, nullptr, t_e, t_r, t_rend, ntiles, H);
  // gemm2: ys = H@W2 scatter. grid = 4 nb * 80 bt
  gemm256_kernel<false><<<4 * MAXT, 512, 65536, stream>>>(
      H, W2T, nullptr, nullptr, slot_list, t_e, t_r, t_rend, ntiles, ys);
  combine_kernel<<<(T_TOK * DMODEL / 8) / 256, 256, 0, stream>>>(ys, wts, sel, b2, out);
}

// Round 22
// 586.983 us; speedup vs baseline: 1.3974x; 1.2658x over previous
//
#include <hip/hip_runtime.h>
#include <stdint.h>

#define T_TOK 8192
#define DMODEL 1024
#define FDIM 4096
#define NEXP 8
#define NROWS 16384      // T_TOK * K
#define MAXT 80          // max 256-row tiles

// prep_kernel block ranges
#define GATE_BLKS 2048                  // T_TOK/4
#define CVT_BLKS  4096                  // T*D/8/256
#define TRP_BLKS  2048                  // 1024 w1-groups + 1024 w2-groups (8 tiles each)
#define PREP_BLKS (GATE_BLKS + CVT_BLKS + TRP_BLKS)

typedef __bf16 bf16x8 __attribute__((ext_vector_type(8)));
typedef float f32x4 __attribute__((ext_vector_type(4)));
#define AS1 __attribute__((address_space(1)))
#define AS3 __attribute__((address_space(3)))

__device__ __forceinline__ unsigned short f2bf(float f) {
  union { float f; unsigned u; } v; v.f = f;
  unsigned r = v.u + 0x7fffu + ((v.u >> 16) & 1u);
  return (unsigned short)(r >> 16);
}
__device__ __forceinline__ float bflo(unsigned u) {
  union { unsigned u; float f; } v; v.u = u << 16; return v.f;
}
__device__ __forceinline__ float bfhi(unsigned u) {
  union { unsigned u; float f; } v; v.u = u & 0xffff0000u; return v.f;
}

// ---- pipelined tile transpose (verified R18): f32 -> chunked [kt][n][64] bf16
__device__ __forceinline__ void tile_tr_pipe(
    const float* __restrict__ in, unsigned short* __restrict__ out,
    int Kdim, int Ndim, int e, int kt, int ng0, float* lds)
{
  size_t ebase = (size_t)e * Kdim * Ndim;
  const int tid = threadIdx.x, lane = tid & 63, wave = tid >> 6;
  const int lr = lane >> 4, lc = (lane & 15) * 4;
  auto stage = [&](int i, int b) {
    const int n0 = (ng0 + i) * 64;
#pragma unroll
    for (int it = 0; it < 4; ++it) {
      int c = wave * 4 + it;                        // 1KB chunk = 4 k-rows
      const float* src = in + ebase + (size_t)(kt * 64 + c * 4 + lr) * Ndim + n0 + lc;
      __builtin_amdgcn_global_load_lds(
          (const AS1 void*)src,
          (AS3 void*)((char*)lds + b * 16384 + c * 1024), 16, 0, 0);
    }
  };
  stage(0, 0);
  for (int i = 0; i < 8; ++i) {
    const int b = i & 1;
    if (i + 1 < 8) {
      stage(i + 1, b ^ 1);
      asm volatile("s_waitcnt vmcnt(4)" ::: "memory");
    } else {
      asm volatile("s_waitcnt vmcnt(0)" ::: "memory");
    }
    __syncthreads();
    const float* L = lds + b * 4096;
    int n = tid >> 2, k16 = (tid & 3) * 16;
    union { unsigned short h[16]; uint4 q[2]; } pk;
#pragma unroll
    for (int j = 0; j < 16; ++j)
      pk.h[j] = f2bf(L[(k16 + j) * 64 + n]);
    unsigned short* dst = out + ebase + ((size_t)kt * Ndim + (ng0 + i) * 64 + n) * 64 + k16;
    *(uint4*)dst = pk.q[0];
    *(uint4*)(dst + 8) = pk.q[1];
    __syncthreads();                                // phase2 done before buf reuse
  }
}

// ---------------- fused prep: gate || f32->bf16 cvt || both W transposes ------
__global__ __launch_bounds__(256) void prep_kernel(
    const float* __restrict__ gx, const float* __restrict__ Wg,
    const float* __restrict__ bg, int* __restrict__ sel,
    float* __restrict__ wts,
    const float* __restrict__ inputs, unsigned short* __restrict__ Xb,
    const float* __restrict__ w1, unsigned short* __restrict__ W1T,
    const float* __restrict__ w2, unsigned short* __restrict__ W2T)
{
  __shared__ __align__(16) float tr_lds[2 * 64 * 64];   // 32 KB dbuf
  int b = blockIdx.x;
  if (b < GATE_BLKS) {
    int t = b * 4 + (threadIdx.x >> 6);
    int lane = threadIdx.x & 63;
    const float* row = gx + (size_t)t * DMODEL;
    float acc[NEXP];
#pragma unroll
    for (int e = 0; e < NEXP; ++e) acc[e] = 0.f;
    for (int d = lane; d < DMODEL; d += 64) {
      float x = row[d];
      const float* wgr = Wg + (size_t)d * NEXP;
#pragma unroll
      for (int e = 0; e < NEXP; ++e) acc[e] += x * wgr[e];
    }
#pragma unroll
    for (int off = 32; off > 0; off >>= 1) {
#pragma unroll
      for (int e = 0; e < NEXP; ++e) acc[e] += __shfl_down(acc[e], off);
    }
    if (lane == 0) {
      float lg[NEXP];
#pragma unroll
      for (int e = 0; e < NEXP; ++e) lg[e] = acc[e] + bg[e];
      int i1 = 0; float v1 = lg[0];
#pragma unroll
      for (int e = 1; e < NEXP; ++e) if (lg[e] > v1) { v1 = lg[e]; i1 = e; }
      int i2 = -1; float v2 = -3.4e38f;
#pragma unroll
      for (int e = 0; e < NEXP; ++e) if (e != i1 && lg[e] > v2) { v2 = lg[e]; i2 = e; }
      float ez = __expf(v2 - v1);           // v2 <= v1
      float s = 1.f / (1.f + ez);
      sel[t*2] = i1; sel[t*2+1] = i2;
      wts[t*2] = s;  wts[t*2+1] = ez * s;   // no atomics: counts from sel in scan
    }
  } else if (b < GATE_BLKS + CVT_BLKS) {
    int i = (b - GATE_BLKS) * 256 + threadIdx.x;
    const float4* in4 = (const float4*)inputs;
    float4 v0 = in4[(size_t)i*2], v1 = in4[(size_t)i*2 + 1];
    union { unsigned short u[8]; uint4 q; } r;
    r.u[0]=f2bf(v0.x); r.u[1]=f2bf(v0.y); r.u[2]=f2bf(v0.z); r.u[3]=f2bf(v0.w);
    r.u[4]=f2bf(v1.x); r.u[5]=f2bf(v1.y); r.u[6]=f2bf(v1.z); r.u[7]=f2bf(v1.w);
    ((uint4*)Xb)[i] = r.q;
  } else {
    int bp = b - (GATE_BLKS + CVT_BLKS);   // 0..2047
    if (bp < 1024) {
      // w1 [E][K=1024][N=4096]: 128 groups/expert = kt(16) x nggrp(8)
      int e = bp >> 7, rem = bp & 127;
      tile_tr_pipe(w1, W1T, DMODEL, FDIM, e, rem >> 3, (rem & 7) * 8, tr_lds);
    } else {
      // w2 [E][K=4096][N=1024]: 128 groups/expert = kt(64) x nggrp(2)
      bp -= 1024;
      int e = bp >> 7, rem = bp & 127;
      tile_tr_pipe(w2, W2T, FDIM, DMODEL, e, rem >> 1, (rem & 1) * 8, tr_lds);
    }
  }
}

// ---------------- hist(sel) + offsets + 256-row tile table (1 block) ----------
__global__ __launch_bounds__(256) void scan_build_kernel(
    const int* __restrict__ sel, int* __restrict__ offsets,
    int* __restrict__ ntiles, int* __restrict__ t_e, int* __restrict__ t_r,
    int* __restrict__ t_rend)
{
  __shared__ int sc[8], soff[9], stile[9];
  int tid = threadIdx.x;
  if (tid < 8) sc[tid] = 0;
  __syncthreads();
  int cnt[NEXP];
#pragma unroll
  for (int e = 0; e < NEXP; ++e) cnt[e] = 0;
  for (int i = tid; i < NROWS; i += 256) {
    int v = sel[i];
#pragma unroll
    for (int e = 0; e < NEXP; ++e) cnt[e] += (v == e) ? 1 : 0;
  }
#pragma unroll
  for (int e = 0; e < NEXP; ++e) if (cnt[e]) atomicAdd(&sc[e], cnt[e]);
  __syncthreads();
  if (tid == 0) {
    int off = 0, tl = 0;
#pragma unroll
    for (int e = 0; e < NEXP; ++e) {
      soff[e] = off; stile[e] = tl;
      off += sc[e];
      tl += (sc[e] + 255) >> 8;
    }
    soff[8] = off; stile[8] = tl;
  }
  __syncthreads();
  int ntot = stile[8];
  for (int idx = tid; idx < ntot; idx += 256) {
    int e = 0;
#pragma unroll
    for (int q = 0; q < NEXP; ++q) if (idx >= stile[q + 1]) e = q + 1;
    int r = (idx - stile[e]) * 256;
    t_e[idx] = e; t_r[idx] = soff[e] + r; t_rend[idx] = soff[e] + sc[e];
  }
  if (tid < 9) offsets[tid] = soff[tid];
  if (tid == 0) *ntiles = ntot;
}

// ---------------- scatter: wave-aggregated per-expert atomics -----------------
__global__ __launch_bounds__(256) void scatter_kernel(
    const int* __restrict__ sel, int* __restrict__ cursors,
    const int* __restrict__ offsets, int* __restrict__ token_list,
    int* __restrict__ slot_list)
{
  int t = blockIdx.x * 256 + threadIdx.x;
  int lane = threadIdx.x & 63;
  unsigned long long ltmask = (lane == 63) ? 0x7fffffffffffffffull
                                           : ((1ull << lane) - 1ull);
#pragma unroll
  for (int k = 0; k < 2; ++k) {
    int e = sel[t*2 + k];
#pragma unroll
    for (int ex = 0; ex < NEXP; ++ex) {
      unsigned long long m = __ballot(e == ex);
      if (m == 0ull) continue;
      if (e == ex) {
        int leader = __ffsll((unsigned long long)m) - 1;
        int cnt = __popcll(m);
        int base = 0;
        if (lane == leader) base = atomicAdd(&cursors[ex], cnt);
        base = __shfl(base, leader);
        int r = offsets[ex] + base + __popcll(m & ltmask);
        token_list[r] = t;
        slot_list[r] = t*2 + k;
      }
    }
  }
}

// ---------------- grouped GEMM 256x256, BK=64, overlap-phase schedule ---------
// (verified R19 — best configuration; held as final)
// ONE barrier/phase; quad p+1's ds_reads issued at END of phase p (overlap
// other waves' MFMA); every confirm is 2 PHASES after issue with a barrier in
// between (cross-wave safe, zero-stall).
// Stage plan (tile kt stages kt+1): P0:{A0,B0} P1:{B1} P2:{A1} P3:none.
// Waits: P0 vmcnt(4) [confirms A1(kt)]; P2 vmcnt(4) [A0,B0(kt+1)];
//        P3 vmcnt(2) [B1(kt+1)]. Gray-code regs: bR0 lives all tile; aR A0->A1.
template<bool G1>
__global__ __launch_bounds__(512, 2) void gemm256_kernel(
    const unsigned short* __restrict__ A, const unsigned short* __restrict__ B,
    const float* __restrict__ b1, const int* __restrict__ token_list,
    const int* __restrict__ slot_list,
    const int* __restrict__ tile_e, const int* __restrict__ tile_r,
    const int* __restrict__ tile_rend, const int* __restrict__ ntiles,
    unsigned short* __restrict__ outp)
{
  constexpr int KDIM = G1 ? DMODEL : FDIM;   // K extent
  constexpr int NKT  = KDIM / 64;
  constexpr int NOUT = G1 ? FDIM : DMODEL;   // output row width
  constexpr int KTB  = NOUT * 64;            // B k-tile stride (elements)

  int bid = blockIdx.x;
  int nb, bt;
  if constexpr (G1) {                        // 16 nb-panels: pin 2 per XCD, bt-major
    int xcd = bid & 7, idx = bid >> 3;
    nb = xcd * 2 + (idx & 1);
    bt = idx >> 1;
  } else {                                   // 4 nb-panels, bt-major
    nb = bid & 3;
    bt = bid >> 2;
  }
  if (bt >= *ntiles) return;
  const int e = tile_e[bt], row0 = tile_r[bt], rend = tile_rend[bt];
  const int n0 = nb * 256;

  const int tid = threadIdx.x, lane = tid & 63, wave = tid >> 6;
  extern __shared__ __align__(16) char smem[];   // 131072 B

  const int lr8 = lane >> 3, g8 = lane & 7, ch = g8 ^ lr8;

  int mA[2], mB[2];
#pragma unroll
  for (int p = 0; p < 2; ++p)
    mA[p] = (wave < 4) ? (p*64 + wave*16) : (128 + p*64 + (wave-4)*16);
#pragma unroll
  for (int nh = 0; nh < 2; ++nh)
    mB[nh] = (wave >> 1)*64 + nh*32 + (wave & 1)*16;

  const unsigned short* eB = B + (size_t)e * KDIM * NOUT;
  unsigned aoffs[2][2], boffs[2][2];
#pragma unroll
  for (int p = 0; p < 2; ++p)
#pragma unroll
    for (int l = 0; l < 2; ++l) {
      int m = mA[p] + l*8 + lr8;
      int row = row0 + m; if (row > NROWS - 1) row = NROWS - 1;
      int arow = G1 ? token_list[row] : row;
      aoffs[p][l] = (unsigned)arow * KDIM + ch*8;
      int mb = mB[p] + l*8 + lr8;
      boffs[p][l] = (unsigned)((n0 + mb) * 64 + ch*8);
    }

  auto stage_half = [&](int p, int ktn, int bsel) {
    char* base = smem + bsel * 65536;
    if (p < 2) {
      const int kb = ktn * 64;
#pragma unroll
      for (int l = 0; l < 2; ++l)
        __builtin_amdgcn_global_load_lds(
            (const AS1 void*)(A + aoffs[p][l] + kb),
            (AS3 void*)(base + ((mA[p] + l*8) << 7)), 16, 0, 0);
    } else {
      const int nh = p - 2;
      const unsigned short* bk = eB + (size_t)ktn * KTB;
#pragma unroll
      for (int l = 0; l < 2; ++l)
        __builtin_amdgcn_global_load_lds(
            (const AS1 void*)(bk + boffs[nh][l]),
            (AS3 void*)(base + 32768 + ((mB[nh] + l*8) << 7)), 16, 0, 0);
    }
  };

  f32x4 acc[8][4] = {};
  bf16x8 aR[4][2];        // current A-half: 4 row-frags x 2 k-slices
  bf16x8 bR[2][2][2];     // both B-halves: [nh][jj][ks]
  const int wr = wave >> 2, wc = wave & 3;
  const int lm = lane & 15, lk = lane >> 4, l7 = lane & 7;
  const unsigned abase = (unsigned)(wr*128 + lm) * 128;
  const unsigned bbase = 32768u + (unsigned)(wc*64 + lm) * 128;
  const unsigned kx0 = (unsigned)((lk ^ l7) << 4);
  const unsigned kx1 = (unsigned)(((4 + lk) ^ l7) << 4);

  auto rdA = [&](const char* base, int mh) {
#pragma unroll
    for (int i = 0; i < 4; ++i) {
      const char* pA = base + abase + mh*8192 + i*2048;
      aR[i][0] = *(const bf16x8*)(pA + kx0);
      aR[i][1] = *(const bf16x8*)(pA + kx1);
    }
  };
  auto rdB = [&](const char* base, int nh) {
#pragma unroll
    for (int jj = 0; jj < 2; ++jj) {
      const char* pB = base + bbase + nh*4096 + jj*2048;
      bR[nh][jj][0] = *(const bf16x8*)(pB + kx0);
      bR[nh][jj][1] = *(const bf16x8*)(pB + kx1);
    }
  };
  auto mm = [&](int mh, int nh) {
    __builtin_amdgcn_s_setprio(1);
#pragma unroll
    for (int i = 0; i < 4; ++i)
#pragma unroll
      for (int jj = 0; jj < 2; ++jj) {
        acc[mh*4+i][nh*2+jj] = __builtin_amdgcn_mfma_f32_16x16x32_bf16(
            aR[i][0], bR[nh][jj][0], acc[mh*4+i][nh*2+jj], 0, 0, 0);
        acc[mh*4+i][nh*2+jj] = __builtin_amdgcn_mfma_f32_16x16x32_bf16(
            aR[i][1], bR[nh][jj][1], acc[mh*4+i][nh*2+jj], 0, 0, 0);
      }
    __builtin_amdgcn_s_setprio(0);
  };

  // prologue: stage tile0 A0,B0,B1,A1; confirm A0,B0,B1; barrier; rd quad0
  stage_half(0, 0, 0);   // A0
  stage_half(2, 0, 0);   // B0
  stage_half(3, 0, 0);   // B1
  stage_half(1, 0, 0);   // A1
  asm volatile("s_waitcnt vmcnt(2)" ::: "memory");
  __builtin_amdgcn_s_barrier();
  __builtin_amdgcn_sched_barrier(0);
  rdA((const char*)smem, 0); rdB((const char*)smem, 0);
  __builtin_amdgcn_sched_barrier(0);

  for (int kt = 0; kt < NKT; ++kt) {
    const int b = kt & 1, nxt = b ^ 1;
    const char* base = smem + b * 65536;
    const char* nbase = smem + nxt * 65536;
    const bool pre = (kt + 1 < NKT);
    // ---- P0: mm(0,0); stage A0,B0(kt+1); confirm A1(kt); rd B1(kt) ----
    __builtin_amdgcn_s_barrier();
    asm volatile("s_waitcnt lgkmcnt(0)" ::: "memory");
    __builtin_amdgcn_sched_barrier(0);
    mm(0, 0);
    if (pre) {
      stage_half(0, kt + 1, nxt);
      stage_half(2, kt + 1, nxt);
      asm volatile("s_waitcnt vmcnt(4)" ::: "memory");
    } else {
      asm volatile("s_waitcnt vmcnt(0)" ::: "memory");
    }
    rdB(base, 1);
    __builtin_amdgcn_sched_barrier(0);
    // ---- P1: mm(0,1); stage B1(kt+1); rd A1(kt) ----
    __builtin_amdgcn_s_barrier();
    asm volatile("s_waitcnt lgkmcnt(0)" ::: "memory");
    __builtin_amdgcn_sched_barrier(0);
    mm(0, 1);
    if (pre) stage_half(3, kt + 1, nxt);
    rdA(base, 1);
    __builtin_amdgcn_sched_barrier(0);
    // ---- P2: mm(1,1); stage A1(kt+1); confirm A0,B0(kt+1) ----
    __builtin_amdgcn_s_barrier();
    asm volatile("s_waitcnt lgkmcnt(0)" ::: "memory");
    __builtin_amdgcn_sched_barrier(0);
    mm(1, 1);
    if (pre) {
      stage_half(1, kt + 1, nxt);
      asm volatile("s_waitcnt vmcnt(4)" ::: "memory");
    }
    __builtin_amdgcn_sched_barrier(0);
    // ---- P3: mm(1,0); confirm B1(kt+1); rd A0,B0(kt+1) ----
    __builtin_amdgcn_s_barrier();
    __builtin_amdgcn_sched_barrier(0);
    mm(1, 0);
    if (pre) {
      asm volatile("s_waitcnt vmcnt(2)" ::: "memory");
      rdA(nbase, 0); rdB(nbase, 0);
    }
    __builtin_amdgcn_sched_barrier(0);
  }

  asm volatile("" ::: "memory");
  float bias[4] = {};
  if constexpr (G1) {
#pragma unroll
    for (int j = 0; j < 4; ++j) bias[j] = b1[(size_t)e * FDIM + n0 + wc*64 + j*16 + lm];
  }

  // epilogue: 8 chunks of 32 rows; [gelu] -> f32 LDS (stride 260) -> bf16 x8
  float* eps = (float*)smem;
#pragma unroll
  for (int c = 0; c < 8; ++c) {
    __syncthreads();
    if (wr == (c >> 2)) {
#pragma unroll
      for (int ii = 0; ii < 2; ++ii) {
        const int mi = (c & 3) * 2 + ii;
#pragma unroll
        for (int j = 0; j < 4; ++j) {
#pragma unroll
          for (int r = 0; r < 4; ++r) {
            float v = acc[mi][j][r];
            if constexpr (G1) {
              v += bias[j];
              float z2 = 1.5957691216f * (v + 0.044715f * v * v * v);
              v = v / (1.f + __expf(-z2));
            }
            eps[(ii*16 + lk*4 + r) * 260 + wc*64 + j*16 + lm] = v;
          }
        }
      }
    }
    __syncthreads();
#pragma unroll
    for (int u = 0; u < 2; ++u) {
      int item = u * 512 + tid;               // 1024 items: 32 rows x 32 octs
      int lrow = item >> 5, c8 = (item & 31) * 8;
      int gr = row0 + c * 32 + lrow;
      if (gr < rend) {
        float4 v0 = *(const float4*)&eps[lrow * 260 + c8];
        float4 v1 = *(const float4*)&eps[lrow * 260 + c8 + 4];
        union { unsigned short u[8]; uint4 q; } pk;
        pk.u[0]=f2bf(v0.x); pk.u[1]=f2bf(v0.y); pk.u[2]=f2bf(v0.z); pk.u[3]=f2bf(v0.w);
        pk.u[4]=f2bf(v1.x); pk.u[5]=f2bf(v1.y); pk.u[6]=f2bf(v1.z); pk.u[7]=f2bf(v1.w);
        size_t orow;
        if constexpr (G1) orow = (size_t)gr * FDIM;
        else              orow = (size_t)slot_list[gr] * DMODEL;
        *(uint4*)(outp + orow + n0 + c8) = pk.q;
      }
    }
  }
}

// ---------------- combine: out = sum_k w_k*(y_k + b2[e_k]) --------------------
__global__ __launch_bounds__(256) void combine_kernel(
    const unsigned short* __restrict__ ys, const float* __restrict__ wts,
    const int* __restrict__ sel, const float* __restrict__ b2,
    float* __restrict__ out)
{
  int i = blockIdx.x * 256 + threadIdx.x;   // over T*D/8
  int t = i >> 7, d8 = i & 127;
  float w0 = wts[t*2], w1 = wts[t*2 + 1];
  int e0 = sel[t*2], e1 = sel[t*2 + 1];
  const uint4* ys4 = (const uint4*)ys;
  uint4 ya = ys4[(size_t)(t*2) * 128 + d8];
  uint4 yb = ys4[(size_t)(t*2 + 1) * 128 + d8];
  const float4* b24 = (const float4*)b2;
  float4 c0a = b24[e0*256 + d8*2], c0b = b24[e0*256 + d8*2 + 1];
  float4 c1a = b24[e1*256 + d8*2], c1b = b24[e1*256 + d8*2 + 1];
  float4 o0, o1;
  o0.x = w0*(bflo(ya.x)+c0a.x) + w1*(bflo(yb.x)+c1a.x);
  o0.y = w0*(bfhi(ya.x)+c0a.y) + w1*(bfhi(yb.x)+c1a.y);
  o0.z = w0*(bflo(ya.y)+c0a.z) + w1*(bflo(yb.y)+c1a.z);
  o0.w = w0*(bfhi(ya.y)+c0a.w) + w1*(bfhi(yb.y)+c1a.w);
  o1.x = w0*(bflo(ya.z)+c0b.x) + w1*(bflo(yb.z)+c1b.x);
  o1.y = w0*(bfhi(ya.z)+c0b.y) + w1*(bfhi(yb.z)+c1b.y);
  o1.z = w0*(bflo(ya.w)+c0b.z) + w1*(bflo(yb.w)+c1b.z);
  o1.w = w0*(bfhi(ya.w)+c0b.w) + w1*(bfhi(yb.w)+c1b.w);
  float4* out4 = (float4*)out;
  out4[(size_t)t * 256 + d8*2]     = o0;
  out4[(size_t)t * 256 + d8*2 + 1] = o1;
}

// ---------------- host ---------------------------------------------------------
extern "C" void kernel_launch(void* const* d_in, const int* in_sizes, int n_in,
                              void* d_out, int out_size, void* d_ws, size_t ws_size,
                              hipStream_t stream)
{
  const float* gate_inputs = (const float*)d_in[0];
  const float* inputs      = (const float*)d_in[1];
  const float* Wg          = (const float*)d_in[2];
  const float* bg          = (const float*)d_in[3];
  const float* w1          = (const float*)d_in[4];
  const float* b1          = (const float*)d_in[5];
  const float* w2          = (const float*)d_in[6];
  const float* b2          = (const float*)d_in[7];
  float* out = (float*)d_out;

  char* ws = (char*)d_ws;
  size_t o = 0;
  auto carve = [&](size_t bytes) { void* p = ws + o; o += (bytes + 255) & ~(size_t)255; return p; };
  unsigned short* Xb  = (unsigned short*)carve((size_t)T_TOK * DMODEL * 2);
  unsigned short* W1T = (unsigned short*)carve((size_t)NEXP * FDIM * DMODEL * 2);
  unsigned short* W2T = (unsigned short*)carve((size_t)NEXP * DMODEL * FDIM * 2);
  unsigned short* H   = (unsigned short*)carve((size_t)NROWS * FDIM * 2);
  unsigned short* ys  = (unsigned short*)carve((size_t)NROWS * DMODEL * 2);
  int*   sel          = (int*)carve((size_t)NROWS * 4);
  float* wts          = (float*)carve((size_t)NROWS * 4);
  int*   token_list   = (int*)carve((size_t)(NROWS + 256) * 4);
  int*   slot_list    = (int*)carve((size_t)(NROWS + 256) * 4);
  int*   ctrl         = (int*)carve(4096);
  int* cursors = ctrl + 8;        // 8
  int* offsets = ctrl + 16;       // 9
  int* ntiles  = ctrl + 28;       // 1
  int* t_e     = ctrl + 32;
  int* t_r     = ctrl + 32 + MAXT;
  int* t_rend  = ctrl + 32 + 2 * MAXT;

  hipMemsetAsync(ctrl, 0, 64, stream);  // cursors

  prep_kernel<<<PREP_BLKS, 256, 0, stream>>>(
      gate_inputs, Wg, bg, sel, wts,
      inputs, Xb, w1, W1T, w2, W2T);
  scan_build_kernel<<<1, 256, 0, stream>>>(sel, offsets, ntiles, t_e, t_r, t_rend);
  scatter_kernel<<<T_TOK / 256, 256, 0, stream>>>(sel, cursors, offsets, token_list, slot_list);

  hipFuncSetAttribute((const void*)gemm256_kernel<true>,
                      hipFuncAttributeMaxDynamicSharedMemorySize, 131072);
  hipFuncSetAttribute((const void*)gemm256_kernel<false>,
                      hipFuncAttributeMaxDynamicSharedMemorySize, 131072);
  // gemm1: H = gelu(X@W1+b1). grid = 8 xcd * (2 nb-sub * 80 bt)
  gemm256_kernel<true><<<8 * 2 * MAXT, 512, 131072, stream>>>(
      Xb, W1T, b1, token_list, nullptr, t_e, t_r, t_rend, ntiles, H);
  // gemm2: ys = H@W2 scatter. grid = 4 nb * 80 bt
  gemm256_kernel<false><<<4 * MAXT, 512, 131072, stream>>>(
      H, W2T, nullptr, nullptr, slot_list, t_e, t_r, t_rend, ntiles, ys);
  combine_kernel<<<(T_TOK * DMODEL / 8) / 256, 256, 0, stream>>>(ys, wts, sel, b2, out);
}